// Round 5
// baseline (142.436 us; speedup 1.0000x reference)
//
#include <hip/hip_runtime.h>
#include <hip/hip_fp16.h>
#include <stdint.h>

// ---------------------------------------------------------------------------
// CIN block: 3 layers of out[b,k,d] = relu(sum_ij h[b,i,d] feat[b,j,d] W[k,i,j] + b[k])
// GEMM view: m=(b,d), Out[m,k] = sum_i ( diag(h[:,i]) * F ) @ W[:,i,:]^T
// R4: one W stream per CU. Grid 256 (=1 block/CU), block 1024 thr (16 waves),
// tile 64m x 256k (FULL K). Wave w owns kt=w -> W LDS amplification 1x.
// W ring 4x16KB via global_load_lds, counted vmcnt(3), wrapped tail staging.
// h packed pairs [i][lr*2+g] -> one broadcast ds_read_b64 per step.
// Swapped MFMA (A=W, B=diag(h)F); mf=4 via ff[4] resident + perm-dup h.
// ---------------------------------------------------------------------------

typedef _Float16 half8_t __attribute__((ext_vector_type(8)));
typedef float f32x4 __attribute__((ext_vector_type(4)));
typedef uint32_t u32x4 __attribute__((ext_vector_type(4)));

union H8 {
  half8_t h;
  uint32_t u[4];
  u32x4 q;
};

#define AS1 __attribute__((address_space(1)))
#define AS3 __attribute__((address_space(3)))

static __device__ __forceinline__ uint32_t pkmul(uint32_t x, uint32_t y) {
  __half2 a = __builtin_bit_cast(__half2, x);
  __half2 b = __builtin_bit_cast(__half2, y);
  __half2 r = __hmul2(a, b);
  return __builtin_bit_cast(uint32_t, r);
}

// ---- fused prep -------------------------------------------------------------
// blocks [0,512): W0 [k][i][j] f32 -> Wt0 chunks [i][kt][g*16+kr][8 f16]
// blocks [512,2560): W1 ; [2560,4608): W2 ; [4608,4672): feat -> F16 + Fpk
__global__ void prep_kernel(const float* __restrict__ W0, const float* __restrict__ W1,
                            const float* __restrict__ W2, const float* __restrict__ feat,
                            uint16_t* __restrict__ Wt0, uint16_t* __restrict__ Wt1,
                            uint16_t* __restrict__ Wt2,
                            uint16_t* __restrict__ F16, uint16_t* __restrict__ Fpk) {
  int blk = blockIdx.x;
  if (blk < 4608) {
    const float* W; uint16_t* Wt; int FLsh, base;
    if (blk < 512)       { W = W0; Wt = Wt0; FLsh = 5; base = 0; }
    else if (blk < 2560) { W = W1; Wt = Wt1; FLsh = 7; base = 512; }
    else                 { W = W2; Wt = Wt2; FLsh = 7; base = 2560; }
    int idx2 = (blk - base) * 256 + threadIdx.x;
    float2 xy = *(const float2*)(W + (size_t)idx2 * 2);
    int j2 = idx2 & 15;                       // f16-pair index along j
    int i = (idx2 >> 4) & ((1 << FLsh) - 1);
    int k = idx2 >> (4 + FLsh);
    __half2 h2 = __floats2half2_rn(xy.x, xy.y);
    int g = j2 >> 2, kr = k & 15, kt = k >> 4;
    uint32_t* wt32 = (uint32_t*)Wt;
    wt32[(((size_t)i * 16 + kt) * 64 + g * 16 + kr) * 4 + (j2 & 3)] = *(uint32_t*)&h2;
  } else {
    int m = (blk - 4608) * 256 + threadIdx.x;  // 0..16383
    int b = m >> 5, d = m & 31;
    const float* fb = feat + (size_t)b * 1024 + d;
    uint16_t hs[32];
#pragma unroll
    for (int j = 0; j < 32; ++j)
      hs[j] = __half_as_ushort(__float2half(fb[j * 32]));
    // Fpk: [mt][i=j][lr*2+g] u32 halves: lo = row g*32+lr, hi = row g*32+16+lr
    int mt = m >> 6, g = (m >> 5) & 1, plr = m & 15, hf = (m >> 4) & 1;
#pragma unroll
    for (int j = 0; j < 32; ++j)
      Fpk[(((size_t)mt * 32 + j) * 32 + plr * 2 + g) * 2 + hf] = hs[j];
#pragma unroll
    for (int c = 0; c < 4; ++c) {
      u32x4 q;
      q[0] = (uint32_t)hs[c * 8 + 0] | ((uint32_t)hs[c * 8 + 1] << 16);
      q[1] = (uint32_t)hs[c * 8 + 2] | ((uint32_t)hs[c * 8 + 3] << 16);
      q[2] = (uint32_t)hs[c * 8 + 4] | ((uint32_t)hs[c * 8 + 5] << 16);
      q[3] = (uint32_t)hs[c * 8 + 6] | ((uint32_t)hs[c * 8 + 7] << 16);
      *(u32x4*)(F16 + (size_t)m * 32 + c * 8) = q;
    }
  }
}

// ---- fused CIN layer GEMM ---------------------------------------------------
// grid 256 (mt), block 1024 (16 waves). Wave w: 64m x 16k (kt = w), mf=4.
__global__ __launch_bounds__(1024, 4) void gemm_cin(
    const uint32_t* __restrict__ hsrc,  // packed f16-pair source [mt][FL][32]
    int hblock,                         // u32 per-mt block (FL*32)
    const uint16_t* __restrict__ wt,    // [FL][16 kt][64][8] f16 chunks
    const uint16_t* __restrict__ f16m,  // [16384][32] f16
    const float* __restrict__ bias,     // [256]
    uint32_t* __restrict__ hout,        // [mt][128][32] u32 pairs, or null
    float* __restrict__ outp,           // [512][512] f32
    int FL, int obase, int klo) {
  __shared__ __align__(16) char smem[81920];  // [0,64K) W ring x4 ; [64K,80K) h
  char* hlds = smem + 65536;
  const int tid = threadIdx.x;
  const int lane = tid & 63, w = tid >> 6;
  const int lr = lane & 15, hi = lane >> 4;
  const int mt = blockIdx.x;
  const int m0 = mt * 64;
  const int FLm = FL - 1;
  const int phase = ((mt & 7) * (FL >> 3)) & FLm;  // same phase within an XCD

  // --- stage h (packed pairs) into LDS, linear ---
  const uint32_t* hb = hsrc + (size_t)mt * hblock;
  for (int qq = tid; qq < FL * 8; qq += 1024)
    __builtin_amdgcn_global_load_lds((const AS1 uint32_t*)(hb + qq * 4),
                                     (AS3 uint32_t*)(hlds + qq * 16), 16, 0, 0);

  // --- resident F fragments (B-op): col m = m0+mf*16+lr, j-slice hi*8 ---
  H8 ff[4];
#pragma unroll
  for (int mf = 0; mf < 4; ++mf)
    ff[mf].q = *(const u32x4*)(f16m + (size_t)(m0 + mf * 16 + lr) * 32 + hi * 8);

  const char* wbase = (const char*)wt;
  // --- prologue: stage slices phase+0..2 into ring bufs 0..2 ---
#pragma unroll
  for (int r = 0; r < 3; ++r) {
    int sl = (r + phase) & FLm;
    __builtin_amdgcn_global_load_lds(
        (const AS1 uint32_t*)(wbase + (size_t)sl * 16384 + tid * 16),
        (AS3 uint32_t*)(smem + r * 16384 + tid * 16), 16, 0, 0);
  }

  f32x4 acc[4];
#pragma unroll
  for (int mf = 0; mf < 4; ++mf) acc[mf] = (f32x4){0.f, 0.f, 0.f, 0.f};

  for (int t = 0; t < FL; ++t) {
    const int sl = (t + phase) & FLm;
    const int sl3 = (t + 3 + phase) & FLm;  // wrapped tail -> dead buffer, harmless
    __builtin_amdgcn_global_load_lds(
        (const AS1 uint32_t*)(wbase + (size_t)sl3 * 16384 + tid * 16),
        (AS3 uint32_t*)(smem + ((t + 3) & 3) * 16384 + tid * 16), 16, 0, 0);
    asm volatile("s_waitcnt vmcnt(3)" ::: "memory");  // slice t landed, 3 in flight
    asm volatile("s_barrier" ::: "memory");

    const char* buf = smem + (t & 3) * 16384;
    uint2 hq = *(const uint2*)(hlds + sl * 128 + lr * 8);  // broadcast b64
    H8 wf;
    wf.q = *(const u32x4*)(buf + w * 1024 + lane * 16);
    uint32_t e0 = __builtin_amdgcn_perm(hq.x, hq.x, 0x01000100u);  // h[m0+lr]
    uint32_t e1 = __builtin_amdgcn_perm(hq.x, hq.x, 0x03020302u);  // h[m0+16+lr]
    uint32_t e2 = __builtin_amdgcn_perm(hq.y, hq.y, 0x01000100u);  // h[m0+32+lr]
    uint32_t e3 = __builtin_amdgcn_perm(hq.y, hq.y, 0x03020302u);  // h[m0+48+lr]
    H8 a0, a1, a2, a3;
#pragma unroll
    for (int c = 0; c < 4; ++c) {
      a0.u[c] = pkmul(ff[0].u[c], e0);
      a1.u[c] = pkmul(ff[1].u[c], e1);
      a2.u[c] = pkmul(ff[2].u[c], e2);
      a3.u[c] = pkmul(ff[3].u[c], e3);
    }
    acc[0] = __builtin_amdgcn_mfma_f32_16x16x32_f16(wf.h, a0.h, acc[0], 0, 0, 0);
    acc[1] = __builtin_amdgcn_mfma_f32_16x16x32_f16(wf.h, a1.h, acc[1], 0, 0, 0);
    acc[2] = __builtin_amdgcn_mfma_f32_16x16x32_f16(wf.h, a2.h, acc[2], 0, 0, 0);
    acc[3] = __builtin_amdgcn_mfma_f32_16x16x32_f16(wf.h, a3.h, acc[3], 0, 0, 0);
  }

  // ---- epilogue: bias + relu (C: row k_sub = hi*4+r, col m_sub = lr) --------
  f32x4 bv = *(const f32x4*)(bias + w * 16 + hi * 4);
  float v[4][4];  // [mf][r]
#pragma unroll
  for (int mf = 0; mf < 4; ++mf)
#pragma unroll
    for (int r = 0; r < 4; ++r) {
      float x = acc[mf][r] + bv[r];
      v[mf][r] = x > 0.f ? x : 0.f;
    }

  // ---- h panel for next layer: direct global write (k < 128 -> w < 8) -------
  if (hout != nullptr && w < 8) {
#pragma unroll
    for (int r = 0; r < 4; ++r) {
      int k = w * 16 + hi * 4 + r;
#pragma unroll
      for (int g = 0; g < 2; ++g) {
        uint32_t lo = __half_as_ushort(__float2half(v[2 * g][r]));
        uint32_t hi16 = __half_as_ushort(__float2half(v[2 * g + 1][r]));
        hout[(size_t)mt * 4096 + k * 32 + lr * 2 + g] = lo | (hi16 << 16);
      }
    }
  }

  // ---- d-reduction -> output (rows b = mt*2, mt*2+1) -------------------------
  f32x4 s0v, s1v;
#pragma unroll
  for (int r = 0; r < 4; ++r) {
    float x0 = v[0][r] + v[1][r];
    x0 += __shfl_xor(x0, 1); x0 += __shfl_xor(x0, 2);
    x0 += __shfl_xor(x0, 4); x0 += __shfl_xor(x0, 8);
    s0v[r] = x0;
    float x1 = v[2][r] + v[3][r];
    x1 += __shfl_xor(x1, 1); x1 += __shfl_xor(x1, 2);
    x1 += __shfl_xor(x1, 4); x1 += __shfl_xor(x1, 8);
    s1v[r] = x1;
  }
  int k0 = w * 16 + hi * 4;
  if (lr == 0 && k0 >= klo) {
    *(f32x4*)(outp + (size_t)(mt * 2) * 512 + obase + k0 - klo) = s0v;
    *(f32x4*)(outp + (size_t)(mt * 2 + 1) * 512 + obase + k0 - klo) = s1v;
  }
  // drain pending LDS-DMA before endpgm
  asm volatile("s_waitcnt vmcnt(0)" ::: "memory");
}

// ---------------------------------------------------------------------------
extern "C" void kernel_launch(void* const* d_in, const int* in_sizes, int n_in,
                              void* d_out, int out_size, void* d_ws, size_t ws_size,
                              hipStream_t stream) {
  const float* feat = (const float*)d_in[0];
  const float* W0 = (const float*)d_in[1];
  const float* b0 = (const float*)d_in[2];
  const float* W1 = (const float*)d_in[3];
  const float* b1 = (const float*)d_in[4];
  const float* W2 = (const float*)d_in[5];
  const float* b2 = (const float*)d_in[6];
  float* out = (float*)d_out;
  char* ws = (char*)d_ws;

  // workspace layout (bytes)
  uint16_t* Wt0 = (uint16_t*)(ws + 0x000000);  // 512KB
  uint16_t* Wt1 = (uint16_t*)(ws + 0x080000);  // 2MB
  uint16_t* Wt2 = (uint16_t*)(ws + 0x280000);  // 2MB
  uint16_t* F16 = (uint16_t*)(ws + 0x480000);  // 1MB
  uint16_t* Fpk = (uint16_t*)(ws + 0x580000);  // 1MB  [256 mt][32][32] u32
  uint32_t* h1  = (uint32_t*)(ws + 0x680000);  // 4MB  [256 mt][128][32] u32
  uint32_t* h2  = (uint32_t*)(ws + 0xA80000);  // 4MB  (end 14.5MB)

  prep_kernel<<<4672, 256, 0, stream>>>(W0, W1, W2, feat, Wt0, Wt1, Wt2, F16, Fpk);

  // layers: out cols [0,128)=L0 k>=128, [128,256)=L1 k>=128, [256,512)=L2 all k
  gemm_cin<<<256, 1024, 0, stream>>>((const uint32_t*)Fpk, 1024, Wt0, F16, b0,
                                     h1, out, 32, 0, 128);
  gemm_cin<<<256, 1024, 0, stream>>>(h1, 4096, Wt1, F16, b1,
                                     h2, out, 128, 128, 128);
  gemm_cin<<<256, 1024, 0, stream>>>(h2, 4096, Wt2, F16, b2,
                                     (uint32_t*)nullptr, out, 128, 256, 0);
}

// Round 6
// 100.839 us; speedup vs baseline: 1.4125x; 1.4125x over previous
//
#include <hip/hip_runtime.h>
#include <hip/hip_fp16.h>
#include <stdint.h>

// ---------------------------------------------------------------------------
// CIN block: 3 layers of out[b,k,d] = relu(sum_ij h[b,i,d] feat[b,j,d] W[k,i,j] + b[k])
// GEMM view: m=(b,d), Out[m,k] = sum_i ( diag(h[:,i]) * F ) @ W[:,i,:]^T
// R5: W-RESIDENT, ZERO-SYNC main loop. Grid 256 = 16 kg x 16 mg (1 block/CU).
// Block keeps its whole W slice [FL][16 k][32 j] (FL x 1KB <= 128KB) in LDS,
// staged once by global_load_lds + ONE barrier. Each of 16 waves owns one
// 64-row m-tile and runs the FL-step loop with no barriers: per step
// 1 ds_read_b128 (W frag) + perm-dup h + 16 pkmul + 4 MFMA; h streamed from
// global via a 4-deep named-register prefetch ring (dup lanes hit same line).
// Swapped MFMA (A=W, B=diag(h)F) -> m along C lanes: shfl d-reduce, direct
// coalesced global h write. MFMA-bound by construction.
// ---------------------------------------------------------------------------

typedef _Float16 half8_t __attribute__((ext_vector_type(8)));
typedef float f32x4 __attribute__((ext_vector_type(4)));
typedef uint32_t u32x4 __attribute__((ext_vector_type(4)));

union H8 {
  half8_t h;
  uint32_t u[4];
  u32x4 q;
};

#define AS1 __attribute__((address_space(1)))
#define AS3 __attribute__((address_space(3)))

static __device__ __forceinline__ uint32_t pkmul(uint32_t x, uint32_t y) {
  __half2 a = __builtin_bit_cast(__half2, x);
  __half2 b = __builtin_bit_cast(__half2, y);
  __half2 r = __hmul2(a, b);
  return __builtin_bit_cast(uint32_t, r);
}

// ---- fused prep -------------------------------------------------------------
// blocks [0,512): W0 [k][i][j] f32 -> Wt0 chunks [i][kt][g*16+kr][8 f16]
// blocks [512,2560): W1 ; [2560,4608): W2 ; [4608,4672): feat -> F16 + Fpk
__global__ void prep_kernel(const float* __restrict__ W0, const float* __restrict__ W1,
                            const float* __restrict__ W2, const float* __restrict__ feat,
                            uint16_t* __restrict__ Wt0, uint16_t* __restrict__ Wt1,
                            uint16_t* __restrict__ Wt2,
                            uint16_t* __restrict__ F16, uint16_t* __restrict__ Fpk) {
  int blk = blockIdx.x;
  if (blk < 4608) {
    const float* W; uint16_t* Wt; int FLsh, base;
    if (blk < 512)       { W = W0; Wt = Wt0; FLsh = 5; base = 0; }
    else if (blk < 2560) { W = W1; Wt = Wt1; FLsh = 7; base = 512; }
    else                 { W = W2; Wt = Wt2; FLsh = 7; base = 2560; }
    int idx2 = (blk - base) * 256 + threadIdx.x;
    float2 xy = *(const float2*)(W + (size_t)idx2 * 2);
    int j2 = idx2 & 15;                       // f16-pair index along j
    int i = (idx2 >> 4) & ((1 << FLsh) - 1);
    int k = idx2 >> (4 + FLsh);
    __half2 h2 = __floats2half2_rn(xy.x, xy.y);
    int g = j2 >> 2, kr = k & 15, kt = k >> 4;
    uint32_t* wt32 = (uint32_t*)Wt;
    wt32[(((size_t)i * 16 + kt) * 64 + g * 16 + kr) * 4 + (j2 & 3)] = *(uint32_t*)&h2;
  } else {
    int m = (blk - 4608) * 256 + threadIdx.x;  // 0..16383
    int b = m >> 5, d = m & 31;
    const float* fb = feat + (size_t)b * 1024 + d;
    uint16_t hs[32];
#pragma unroll
    for (int j = 0; j < 32; ++j)
      hs[j] = __half_as_ushort(__float2half(fb[j * 32]));
    // Fpk: [mt][j][plr*2+g][hf] pairs: g=0 -> rows (m0+plr, m0+16+plr),
    // g=1 -> rows (m0+32+plr, m0+48+plr)
    int mt = m >> 6, g = (m >> 5) & 1, plr = m & 15, hf = (m >> 4) & 1;
#pragma unroll
    for (int j = 0; j < 32; ++j)
      Fpk[(((size_t)mt * 32 + j) * 32 + plr * 2 + g) * 2 + hf] = hs[j];
#pragma unroll
    for (int c = 0; c < 4; ++c) {
      u32x4 q;
      q[0] = (uint32_t)hs[c * 8 + 0] | ((uint32_t)hs[c * 8 + 1] << 16);
      q[1] = (uint32_t)hs[c * 8 + 2] | ((uint32_t)hs[c * 8 + 3] << 16);
      q[2] = (uint32_t)hs[c * 8 + 4] | ((uint32_t)hs[c * 8 + 5] << 16);
      q[3] = (uint32_t)hs[c * 8 + 6] | ((uint32_t)hs[c * 8 + 7] << 16);
      *(u32x4*)(F16 + (size_t)m * 32 + c * 8) = q;
    }
  }
}

// ---- fused CIN layer GEMM ---------------------------------------------------
// grid 256: bx = mg*16 + kg. Block 1024 thr (16 waves); wave w owns m-tile
// mt = mg*16 + w (64 m-rows) x 16 k-cols (kt = kg), full K. No loop barriers.
__global__ __launch_bounds__(1024) void gemm_cin(
    const uint32_t* __restrict__ hsrc,  // packed f16-pair source [mt][FL][32]
    int hblock,                         // u32 per-mt block (FL*32)
    const uint16_t* __restrict__ wt,    // [FL][16 kt][64][8] f16 chunks
    const uint16_t* __restrict__ f16m,  // [16384][32] f16
    const float* __restrict__ bias,     // [256]
    uint32_t* __restrict__ hout,        // [mt][128][32] u32 pairs, or null
    float* __restrict__ outp,           // [512][512] f32
    int FL, int obase, int klo) {
  __shared__ __align__(16) char smem[131072];  // W slice [FL][1KB], FL<=128
  const int tid = threadIdx.x;
  const int lane = tid & 63, w = tid >> 6;
  const int lr = lane & 15, hi = lane >> 4;
  const int bx = blockIdx.x;
  const int mg = bx >> 4, kg = bx & 15;
  const int mt = mg * 16 + w;   // this wave's m-tile
  const int m0 = mt * 64;
  const int FLm = FL - 1;

  // --- prologue: stage W slice (kt = kg) into LDS, linear [i][1KB] ---
  const char* wbase = (const char*)wt + kg * 1024;
  for (int qq = tid; qq < FL * 64; qq += 1024) {
    __builtin_amdgcn_global_load_lds(
        (const AS1 uint32_t*)(wbase + (size_t)(qq >> 6) * 16384 + (qq & 63) * 16),
        (AS3 uint32_t*)(smem + (size_t)qq * 16), 16, 0, 0);
  }

  // --- resident F fragments (B-op): col m = m0+mf*16+lr, j-slice hi*8 ---
  H8 ff[4];
#pragma unroll
  for (int mf = 0; mf < 4; ++mf)
    ff[mf].q = *(const u32x4*)(f16m + (size_t)(m0 + mf * 16 + lr) * 32 + hi * 8);

  // --- h prefetch ring (4 deep, named regs); lanes 16-63 dup lanes 0-15 ---
  const uint32_t* hb = hsrc + (size_t)mt * hblock + lr * 2;
  uint2 hq0 = *(const uint2*)(hb + 0 * 32);
  uint2 hq1 = *(const uint2*)(hb + (1 & FLm) * 32);
  uint2 hq2 = *(const uint2*)(hb + (2 & FLm) * 32);
  uint2 hq3 = *(const uint2*)(hb + (3 & FLm) * 32);

  f32x4 acc[4];
#pragma unroll
  for (int mf = 0; mf < 4; ++mf) acc[mf] = (f32x4){0.f, 0.f, 0.f, 0.f};

  asm volatile("s_waitcnt vmcnt(0)" ::: "memory");  // W slice (and ff/hq) landed
  __syncthreads();                                   // ONE barrier total

#define CIN_STEP(IDX, HQ)                                                      \
  {                                                                            \
    const int i_ = (IDX);                                                      \
    H8 wf;                                                                     \
    wf.q = *(const u32x4*)(smem + (size_t)i_ * 1024 + lane * 16);              \
    uint32_t e0 = __builtin_amdgcn_perm(HQ.x, HQ.x, 0x01000100u);              \
    uint32_t e1 = __builtin_amdgcn_perm(HQ.x, HQ.x, 0x03020302u);              \
    uint32_t e2 = __builtin_amdgcn_perm(HQ.y, HQ.y, 0x01000100u);              \
    uint32_t e3 = __builtin_amdgcn_perm(HQ.y, HQ.y, 0x03020302u);              \
    HQ = *(const uint2*)(hb + ((i_ + 4) & FLm) * 32);                          \
    H8 a0, a1, a2, a3;                                                         \
    _Pragma("unroll")                                                          \
    for (int c = 0; c < 4; ++c) {                                              \
      a0.u[c] = pkmul(ff[0].u[c], e0);                                         \
      a1.u[c] = pkmul(ff[1].u[c], e1);                                         \
      a2.u[c] = pkmul(ff[2].u[c], e2);                                         \
      a3.u[c] = pkmul(ff[3].u[c], e3);                                         \
    }                                                                          \
    acc[0] = __builtin_amdgcn_mfma_f32_16x16x32_f16(wf.h, a0.h, acc[0], 0, 0, 0); \
    acc[1] = __builtin_amdgcn_mfma_f32_16x16x32_f16(wf.h, a1.h, acc[1], 0, 0, 0); \
    acc[2] = __builtin_amdgcn_mfma_f32_16x16x32_f16(wf.h, a2.h, acc[2], 0, 0, 0); \
    acc[3] = __builtin_amdgcn_mfma_f32_16x16x32_f16(wf.h, a3.h, acc[3], 0, 0, 0); \
  }

  for (int t = 0; t < FL; t += 4) {
    CIN_STEP(t + 0, hq0)
    CIN_STEP(t + 1, hq1)
    CIN_STEP(t + 2, hq2)
    CIN_STEP(t + 3, hq3)
  }
#undef CIN_STEP

  // ---- epilogue: bias + relu (C: row k_sub = hi*4+r, col m_sub = lr) --------
  f32x4 bv = *(const f32x4*)(bias + kg * 16 + hi * 4);
  float v[4][4];  // [mf][r]
#pragma unroll
  for (int mf = 0; mf < 4; ++mf)
#pragma unroll
    for (int r = 0; r < 4; ++r) {
      float x = acc[mf][r] + bv[r];
      v[mf][r] = x > 0.f ? x : 0.f;
    }

  // ---- h panel for next layer: direct coalesced global write ----------------
  if (hout != nullptr && kg < 8) {
#pragma unroll
    for (int r = 0; r < 4; ++r) {
      int k = kg * 16 + hi * 4 + r;
#pragma unroll
      for (int g = 0; g < 2; ++g) {
        uint32_t lo = __half_as_ushort(__float2half(v[2 * g][r]));
        uint32_t hi16 = __half_as_ushort(__float2half(v[2 * g + 1][r]));
        hout[(size_t)mt * 4096 + k * 32 + lr * 2 + g] = lo | (hi16 << 16);
      }
    }
  }

  // ---- d-reduction -> output (rows b = mt*2, mt*2+1) -------------------------
  f32x4 s0v, s1v;
#pragma unroll
  for (int r = 0; r < 4; ++r) {
    float x0 = v[0][r] + v[1][r];
    x0 += __shfl_xor(x0, 1); x0 += __shfl_xor(x0, 2);
    x0 += __shfl_xor(x0, 4); x0 += __shfl_xor(x0, 8);
    s0v[r] = x0;
    float x1 = v[2][r] + v[3][r];
    x1 += __shfl_xor(x1, 1); x1 += __shfl_xor(x1, 2);
    x1 += __shfl_xor(x1, 4); x1 += __shfl_xor(x1, 8);
    s1v[r] = x1;
  }
  int k0 = kg * 16 + hi * 4;
  if (lr == 0 && k0 >= klo) {
    *(f32x4*)(outp + (size_t)(mt * 2) * 512 + obase + k0 - klo) = s0v;
    *(f32x4*)(outp + (size_t)(mt * 2 + 1) * 512 + obase + k0 - klo) = s1v;
  }
}

// ---------------------------------------------------------------------------
extern "C" void kernel_launch(void* const* d_in, const int* in_sizes, int n_in,
                              void* d_out, int out_size, void* d_ws, size_t ws_size,
                              hipStream_t stream) {
  const float* feat = (const float*)d_in[0];
  const float* W0 = (const float*)d_in[1];
  const float* b0 = (const float*)d_in[2];
  const float* W1 = (const float*)d_in[3];
  const float* b1 = (const float*)d_in[4];
  const float* W2 = (const float*)d_in[5];
  const float* b2 = (const float*)d_in[6];
  float* out = (float*)d_out;
  char* ws = (char*)d_ws;

  // workspace layout (bytes)
  uint16_t* Wt0 = (uint16_t*)(ws + 0x000000);  // 512KB
  uint16_t* Wt1 = (uint16_t*)(ws + 0x080000);  // 2MB
  uint16_t* Wt2 = (uint16_t*)(ws + 0x280000);  // 2MB
  uint16_t* F16 = (uint16_t*)(ws + 0x480000);  // 1MB
  uint16_t* Fpk = (uint16_t*)(ws + 0x580000);  // 1MB  [256 mt][32][32] u32
  uint32_t* h1  = (uint32_t*)(ws + 0x680000);  // 4MB  [256 mt][128][32] u32
  uint32_t* h2  = (uint32_t*)(ws + 0xA80000);  // 4MB  (end 14.5MB)

  prep_kernel<<<4672, 256, 0, stream>>>(W0, W1, W2, feat, Wt0, Wt1, Wt2, F16, Fpk);

  // layers: out cols [0,128)=L0 k>=128, [128,256)=L1 k>=128, [256,512)=L2 all k
  gemm_cin<<<256, 1024, 0, stream>>>((const uint32_t*)Fpk, 1024, Wt0, F16, b0,
                                     h1, out, 32, 0, 128);
  gemm_cin<<<256, 1024, 0, stream>>>(h1, 4096, Wt1, F16, b1,
                                     h2, out, 128, 128, 128);
  gemm_cin<<<256, 1024, 0, stream>>>(h2, 4096, Wt2, F16, b2,
                                     (uint32_t*)nullptr, out, 128, 256, 0);
}

// Round 7
// 100.530 us; speedup vs baseline: 1.4169x; 1.0031x over previous
//
#include <hip/hip_runtime.h>
#include <hip/hip_fp16.h>
#include <stdint.h>

// ---------------------------------------------------------------------------
// CIN block: 3 layers of out[b,k,d] = relu(sum_ij h[b,i,d] feat[b,j,d] W[k,i,j] + b[k])
// GEMM view: m=(b,d), Out[m,k] = sum_i ( diag(h[:,i]) * F ) @ W[:,i,:]^T
// R6 (= R5 topology + latency kill): grid 256 = 16 kg x 16 mg (1 block/CU),
// block keeps W slice [FL+3][16k][32j] resident in LDS (dup tail slices ->
// wrap-free immediate offsets). Zero-sync main loop; per step:
//   1 ds_read_b128 (W, register-ring lead-3) + 1 global_dwordx4 (h dup-u32,
//   ring lead-4) + 16 v_pk_mul_f16 + 4 MFMA.  No perms, ~2 addr VALU / 4 steps.
// Swapped MFMA (A=W, B=diag(h)F) -> m on C lanes: shfl d-reduce, direct
// coalesced h-panel write (pre-duplicated for next layer's loads).
// ---------------------------------------------------------------------------

typedef _Float16 half8_t __attribute__((ext_vector_type(8)));
typedef float f32x4 __attribute__((ext_vector_type(4)));
typedef uint32_t u32x4 __attribute__((ext_vector_type(4)));

union H8 {
  half8_t h;
  uint32_t u[4];
  u32x4 q;
};

#define AS1 __attribute__((address_space(1)))
#define AS3 __attribute__((address_space(3)))

static __device__ __forceinline__ uint32_t pkmul(uint32_t x, uint32_t y) {
  __half2 a = __builtin_bit_cast(__half2, x);
  __half2 b = __builtin_bit_cast(__half2, y);
  __half2 r = __hmul2(a, b);
  return __builtin_bit_cast(uint32_t, r);
}

// ---- fused prep -------------------------------------------------------------
// blocks [0,512): W0 [k][i][j] f32 -> Wt0 chunks [i][kt][g*16+kr][8 f16]
// blocks [512,2560): W1 ; [2560,4608): W2
// blocks [4608,4672): feat -> F16 [m][j] and Fdup [mt][36][16 lr][4 mf] dup-u32
__global__ void prep_kernel(const float* __restrict__ W0, const float* __restrict__ W1,
                            const float* __restrict__ W2, const float* __restrict__ feat,
                            uint16_t* __restrict__ Wt0, uint16_t* __restrict__ Wt1,
                            uint16_t* __restrict__ Wt2,
                            uint16_t* __restrict__ F16, uint32_t* __restrict__ Fdup) {
  int blk = blockIdx.x;
  if (blk < 4608) {
    const float* W; uint16_t* Wt; int FLsh, base;
    if (blk < 512)       { W = W0; Wt = Wt0; FLsh = 5; base = 0; }
    else if (blk < 2560) { W = W1; Wt = Wt1; FLsh = 7; base = 512; }
    else                 { W = W2; Wt = Wt2; FLsh = 7; base = 2560; }
    int idx2 = (blk - base) * 256 + threadIdx.x;
    float2 xy = *(const float2*)(W + (size_t)idx2 * 2);
    int j2 = idx2 & 15;                       // f16-pair index along j
    int i = (idx2 >> 4) & ((1 << FLsh) - 1);
    int k = idx2 >> (4 + FLsh);
    __half2 h2 = __floats2half2_rn(xy.x, xy.y);
    int g = j2 >> 2, kr = k & 15, kt = k >> 4;
    uint32_t* wt32 = (uint32_t*)Wt;
    wt32[(((size_t)i * 16 + kt) * 64 + g * 16 + kr) * 4 + (j2 & 3)] = *(uint32_t*)&h2;
  } else {
    int m = (blk - 4608) * 256 + threadIdx.x;  // 0..16383
    int b = m >> 5, d = m & 31;
    const float* fb = feat + (size_t)b * 1024 + d;
    uint16_t hs[32];
#pragma unroll
    for (int j = 0; j < 32; ++j)
      hs[j] = __half_as_ushort(__float2half(fb[j * 32]));
    int mt = m >> 6, mf = (m >> 4) & 3, l2 = m & 15;
    uint32_t* Fd = Fdup + (size_t)mt * 2304 + l2 * 4 + mf;
#pragma unroll
    for (int j = 0; j < 32; ++j) {
      uint32_t du = (uint32_t)hs[j] * 0x10001u;
      Fd[j * 64] = du;
      if (j < 4) Fd[(32 + j) * 64] = du;  // wrap-free tail dup slices
    }
#pragma unroll
    for (int c = 0; c < 4; ++c) {
      u32x4 q;
      q[0] = (uint32_t)hs[c * 8 + 0] | ((uint32_t)hs[c * 8 + 1] << 16);
      q[1] = (uint32_t)hs[c * 8 + 2] | ((uint32_t)hs[c * 8 + 3] << 16);
      q[2] = (uint32_t)hs[c * 8 + 4] | ((uint32_t)hs[c * 8 + 5] << 16);
      q[3] = (uint32_t)hs[c * 8 + 6] | ((uint32_t)hs[c * 8 + 7] << 16);
      *(u32x4*)(F16 + (size_t)m * 32 + c * 8) = q;
    }
  }
}

// ---- fused CIN layer GEMM ---------------------------------------------------
// grid 256: bx = mg*16 + kg. Block 1024 thr (16 waves); wave w owns m-tile
// mt = mg*16 + w (64 m-rows) x 16 k-cols (kt = kg), full K. No loop barriers.
__global__ __launch_bounds__(1024, 4) void gemm_cin(
    const uint32_t* __restrict__ hdup,  // [mt][FL+4][16 lr][4 mf] dup-u32
    int hstride,                        // u32 per-mt block ((FL+4)*64)
    const uint16_t* __restrict__ wt,    // [FL][16 kt][64][8] f16 chunks
    const uint16_t* __restrict__ f16m,  // [16384][32] f16
    const float* __restrict__ bias,     // [256]
    uint32_t* __restrict__ hout,        // [mt][132][16][4] dup-u32, or null
    float* __restrict__ outp,           // [512][512] f32
    int FL, int obase, int klo) {
  __shared__ __align__(16) char smem[134144];  // (FL+3) x 1KB, FL<=128
  const int tid = threadIdx.x;
  const int lane = tid & 63, w = tid >> 6;
  const int lr = lane & 15, hi = lane >> 4;
  const int bx = blockIdx.x;
  const int mg = bx >> 4, kg = bx & 15;
  const int mt = mg * 16 + w;   // this wave's m-tile
  const int m0 = mt * 64;
  const int FLm = FL - 1;

  // --- prologue: stage W slice (kt = kg) into LDS + 3 dup tail slices ---
  const char* wbase = (const char*)wt + kg * 1024;
  const int nq = (FL + 3) * 64;
  for (int qq = tid; qq < nq; qq += 1024) {
    int sl = (qq >> 6) & FLm;  // slices FL..FL+2 duplicate 0..2
    __builtin_amdgcn_global_load_lds(
        (const AS1 uint32_t*)(wbase + (size_t)sl * 16384 + (qq & 63) * 16),
        (AS3 uint32_t*)(smem + (size_t)qq * 16), 16, 0, 0);
  }

  // --- resident F fragments (B-op): col m = m0+mf*16+lr, j-slice hi*8 ---
  H8 ff[4];
#pragma unroll
  for (int mf = 0; mf < 4; ++mf)
    ff[mf].q = *(const u32x4*)(f16m + (size_t)(m0 + mf * 16 + lr) * 32 + hi * 8);

  // --- h dup ring (4 deep); lanes with same lr read same 16B (broadcast) ---
  const uint32_t* hb = hdup + (size_t)mt * hstride + lr * 4;
  u32x4 hrA = *(const u32x4*)(hb + 0 * 64);
  u32x4 hrB = *(const u32x4*)(hb + 1 * 64);
  u32x4 hrC = *(const u32x4*)(hb + 2 * 64);
  u32x4 hrD = *(const u32x4*)(hb + 3 * 64);

  f32x4 acc[4];
#pragma unroll
  for (int mf = 0; mf < 4; ++mf) acc[mf] = (f32x4){0.f, 0.f, 0.f, 0.f};

  asm volatile("s_waitcnt vmcnt(0)" ::: "memory");  // W slice + ff + h ring landed
  __syncthreads();                                   // ONE barrier total

  // --- W register ring, lead 3 (named slots, all offsets immediate) ---
  H8 wr0, wr1, wr2, wr3;
  wr0.q = *(const u32x4*)(smem + 0 * 1024 + lane * 16);
  wr1.q = *(const u32x4*)(smem + 1 * 1024 + lane * 16);
  wr2.q = *(const u32x4*)(smem + 2 * 1024 + lane * 16);

#define CIN_STEP(WRC, HRC, WRN, WOFF, HOFF)                                        \
  {                                                                                \
    uint32_t e0 = HRC[0], e1 = HRC[1], e2 = HRC[2], e3 = HRC[3];                   \
    WRN.q = *(const u32x4*)(wls + (WOFF) * 1024);                                  \
    HRC = *(const u32x4*)(hpt + (HOFF) * 64);                                      \
    H8 a0, a1, a2, a3;                                                             \
    _Pragma("unroll") for (int c = 0; c < 4; ++c) {                                \
      a0.u[c] = pkmul(ff[0].u[c], e0);                                             \
      a1.u[c] = pkmul(ff[1].u[c], e1);                                             \
      a2.u[c] = pkmul(ff[2].u[c], e2);                                             \
      a3.u[c] = pkmul(ff[3].u[c], e3);                                             \
    }                                                                              \
    acc[0] = __builtin_amdgcn_mfma_f32_16x16x32_f16(WRC.h, a0.h, acc[0], 0, 0, 0); \
    acc[1] = __builtin_amdgcn_mfma_f32_16x16x32_f16(WRC.h, a1.h, acc[1], 0, 0, 0); \
    acc[2] = __builtin_amdgcn_mfma_f32_16x16x32_f16(WRC.h, a2.h, acc[2], 0, 0, 0); \
    acc[3] = __builtin_amdgcn_mfma_f32_16x16x32_f16(WRC.h, a3.h, acc[3], 0, 0, 0); \
  }

  for (int t = 0; t < FL; t += 4) {
    const char* wls = smem + (size_t)t * 1024 + lane * 16;
    const uint32_t* hpt = hb + (size_t)t * 64;
    CIN_STEP(wr0, hrA, wr3, 3, 4)
    CIN_STEP(wr1, hrB, wr0, 4, 5)
    CIN_STEP(wr2, hrC, wr1, 5, 6)
    CIN_STEP(wr3, hrD, wr2, 6, 7)
  }
#undef CIN_STEP

  // ---- epilogue: bias + relu (C: row k_sub = hi*4+r, col m_sub = lr) --------
  f32x4 bv = *(const f32x4*)(bias + kg * 16 + hi * 4);
  float v[4][4];  // [mf][r]
#pragma unroll
  for (int mf = 0; mf < 4; ++mf)
#pragma unroll
    for (int r = 0; r < 4; ++r) {
      float x = acc[mf][r] + bv[r];
      v[mf][r] = x > 0.f ? x : 0.f;
    }

  // ---- h panel for next layer: dup-u32, direct coalesced global write -------
  if (hout != nullptr && kg < 8) {
#pragma unroll
    for (int r = 0; r < 4; ++r) {
      int k = kg * 16 + hi * 4 + r;
      uint32_t* hp = hout + ((size_t)mt * 132 + k) * 64 + lr * 4;
      u32x4 du;
#pragma unroll
      for (int mf = 0; mf < 4; ++mf)
        du[mf] = (uint32_t)__half_as_ushort(__float2half(v[mf][r])) * 0x10001u;
      *(u32x4*)hp = du;
      if (kg == 0 && hi == 0) *(u32x4*)(hp + 8192) = du;  // dup slice 128+k
    }
  }

  // ---- d-reduction -> output (rows b = mt*2, mt*2+1) -------------------------
  f32x4 s0v, s1v;
#pragma unroll
  for (int r = 0; r < 4; ++r) {
    float x0 = v[0][r] + v[1][r];
    x0 += __shfl_xor(x0, 1); x0 += __shfl_xor(x0, 2);
    x0 += __shfl_xor(x0, 4); x0 += __shfl_xor(x0, 8);
    s0v[r] = x0;
    float x1 = v[2][r] + v[3][r];
    x1 += __shfl_xor(x1, 1); x1 += __shfl_xor(x1, 2);
    x1 += __shfl_xor(x1, 4); x1 += __shfl_xor(x1, 8);
    s1v[r] = x1;
  }
  int k0 = kg * 16 + hi * 4;
  if (lr == 0 && k0 >= klo) {
    *(f32x4*)(outp + (size_t)(mt * 2) * 512 + obase + k0 - klo) = s0v;
    *(f32x4*)(outp + (size_t)(mt * 2 + 1) * 512 + obase + k0 - klo) = s1v;
  }
}

// ---------------------------------------------------------------------------
extern "C" void kernel_launch(void* const* d_in, const int* in_sizes, int n_in,
                              void* d_out, int out_size, void* d_ws, size_t ws_size,
                              hipStream_t stream) {
  const float* feat = (const float*)d_in[0];
  const float* W0 = (const float*)d_in[1];
  const float* b0 = (const float*)d_in[2];
  const float* W1 = (const float*)d_in[3];
  const float* b1 = (const float*)d_in[4];
  const float* W2 = (const float*)d_in[5];
  const float* b2 = (const float*)d_in[6];
  float* out = (float*)d_out;
  char* ws = (char*)d_ws;

  // workspace layout (bytes)
  uint16_t* Wt0  = (uint16_t*)(ws + 0x000000);   // 512KB
  uint16_t* Wt1  = (uint16_t*)(ws + 0x080000);   // 2MB
  uint16_t* Wt2  = (uint16_t*)(ws + 0x280000);   // 2MB
  uint16_t* F16  = (uint16_t*)(ws + 0x480000);   // 1MB
  uint32_t* Fdup = (uint32_t*)(ws + 0x580000);   // 256*2304*4 = 2.25MB
  uint32_t* h1   = (uint32_t*)(ws + 0x800000);   // 256*8448*4 = 8.25MB
  uint32_t* h2   = (uint32_t*)(ws + 0x1100000);  // 8.25MB (end ~26.5MB)

  prep_kernel<<<4672, 256, 0, stream>>>(W0, W1, W2, feat, Wt0, Wt1, Wt2, F16, Fdup);

  // layers: out cols [0,128)=L0 k>=128, [128,256)=L1 k>=128, [256,512)=L2 all k
  gemm_cin<<<256, 1024, 0, stream>>>(Fdup, 2304, Wt0, F16, b0, h1, out, 32, 0, 128);
  gemm_cin<<<256, 1024, 0, stream>>>(h1, 8448, Wt1, F16, b1, h2, out, 128, 128, 128);
  gemm_cin<<<256, 1024, 0, stream>>>(h2, 8448, Wt2, F16, b2, (uint32_t*)nullptr,
                                     out, 128, 256, 0);
}